// Round 17
// baseline (5116.526 us; speedup 1.0000x reference)
//
#include <hip/hip_runtime.h>
#include <hip/hip_bf16.h>

// C_VAE_NET: 2-layer LSTM encoder -> reparam -> 2-layer LSTM decoder -> dense.
// B=512, T=128, D=128, Z=64, U=512, gates 4U=2048.
// Round 16: arrival-ordered h-MFMA.
//  - MFMA K-dim == producer dim: producer p's 16 units are k-cols [16p,16p+16).
//    Per k0-iter (2 producers), poll only those 2 flags (snapshot ballot says
//    most are ready), load A-frags DIRECT from XCD-local L2 into registers
//    (8 iters in flight per K-half), MFMA from registers. No wait-for-all,
//    no 64KB stage, no hL, 1 barrier/step (hstage parity double-buffered).
//  - Wx now LDS-resident for ALL layers (freed 64KB). LDS 132KB -> 1 blk/CU.
//  - proven kept: XCD roster, plain-store/plain-load h via local L2, MALL
//    flags + s_sleep(1), wave0 store+vmcnt+signal tail, c-state in regs.

#define B_  512
#define T_  128
#define D_  128
#define Z_  64
#define U_  512
#define G4_ 2048

typedef __attribute__((ext_vector_type(8))) short short8; // 8 x bf16
typedef __attribute__((ext_vector_type(4))) float f32x4;
typedef unsigned long long ull;

__device__ __forceinline__ float tanhf_(float x){ return 2.0f / (1.0f + __expf(-2.0f * x)) - 1.0f; }

// ---------------------------------------------------------------------------
// prep kernels
// ---------------------------------------------------------------------------

// x [B][T][D] fp32 -> xb [T][B][D] bf16
__global__ void convert_transpose(const float* __restrict__ src, __hip_bfloat16* __restrict__ dst) {
    int i = blockIdx.x * 256 + threadIdx.x;          // dst-linear over T*B*D
    if (i >= B_ * T_ * D_) return;
    int t = i >> 16;                                  // /(B*D)=65536
    int rem = i & 65535;
    int b = rem >> 7, d = rem & 127;                  // D=128
    dst[i] = __float2bfloat16(src[((size_t)b * T_ + t) * D_ + d]);
}

// dst[n][koff+k] = bf16(src[k][pcol(n)]) ; src is [K][Nsrc] row-major fp32.
// perm: pcol = (n&3)*512 + (n>>2)  (gate-interleave i,f,c,o per unit), else n.
__global__ void conv_weight(const float* __restrict__ src, __hip_bfloat16* __restrict__ dst,
                            int K, int Nrows, int Nsrc, int ldd, int koff, int perm) {
    int idx = blockIdx.x * 256 + threadIdx.x;
    if (idx >= K * Nrows) return;
    int n = idx / K, k = idx - n * K;
    int pc = perm ? ((n & 3) * 512 + (n >> 2)) : n;
    dst[(size_t)n * ldd + koff + k] = __float2bfloat16(src[(size_t)k * Nsrc + pc]);
}

__global__ void conv_bias(const float* __restrict__ src, float* __restrict__ dst) {
    int n = blockIdx.x * 256 + threadIdx.x;
    if (n < G4_) dst[n] = src[(n & 3) * 512 + (n >> 2)];
}

// ---------------------------------------------------------------------------
// persistent LSTM layer, XCD-local groups, arrival-ordered h-MFMA.
// hs  : [T][B][U] bf16 (wave0 contiguous plain stores -> local L2 write-back)
// xin : [T][B][DIN] bf16 (plain cached loads)
// WT  : [2048][512+DIN] bf16, row n = permuted gate col; cols = [Wh | Wx]
// ctrl: per-layer [8 roster][pad->64][MALL flags 8*32*16], pre-zeroed
// grid 256 blocks x 256 thr; 132KB LDS => 1 block/CU => 32 blocks/XCD.
// ---------------------------------------------------------------------------
template <int DIN>
__global__ __launch_bounds__(256, 1) void lstm_layer_persist(
    __hip_bfloat16* __restrict__ hs,
    const __hip_bfloat16* __restrict__ xin,
    const __hip_bfloat16* __restrict__ WT,
    const float* __restrict__ bias,
    unsigned* __restrict__ ctrl) {
    constexpr int LDW = U_ + DIN;
    constexpr int SX = DIN * 2;                   // Wx LDS row byte stride
    __shared__ __hip_bfloat16 WhL[64 * 512];      // 64KB, swizzled
    __shared__ __hip_bfloat16 WxL[64 * 512];      // 64KB alloc (DIN<=512), swizzled
    __shared__ __hip_bfloat16 hstage[2][64 * 16]; // 2x2KB, parity-buffered
    __shared__ unsigned sj;

    const int tid = threadIdx.x;
    const int w = tid >> 6, l = tid & 63, lr = l & 15, lq = l >> 4;
    const int wm = (w >> 1) * 32, wn = (w & 1) * 32;
    const int gate = l & 3;

    // ---- physical XCD id -> group; roster slot -> column tile ----
    unsigned xcc;
    asm volatile("s_getreg_b32 %0, hwreg(HW_REG_XCC_ID)" : "=s"(xcc));
    const int g = (int)(xcc & 7);
    if (tid == 0)
        sj = __hip_atomic_fetch_add(ctrl + g, 1u, __ATOMIC_RELAXED, __HIP_MEMORY_SCOPE_AGENT);
    __syncthreads();
    const int j = (int)(sj & 31);
    const int m0 = g * 64, n0 = j * 64;
    unsigned* gflags = ctrl + 64 + g * (32 * 16);
    unsigned* myflag = gflags + j * 16;

    // ---- stage Wh and Wx into LDS, XOR-swizzled ----
    for (int idx = tid; idx < 64 * 64; idx += 256) {
        int row = idx >> 6, ch = idx & 63;
        short8 v = *(const short8*)(WT + (size_t)(n0 + row) * LDW + ch * 8);
        int byte = row * 1024 + ((ch * 16) ^ ((row & 7) << 4));
        *(short8*)((char*)WhL + byte) = v;
    }
    {
        constexpr int CHX = DIN / 8;
        for (int idx = tid; idx < 64 * CHX; idx += 256) {
            int row = idx / CHX, ch = idx - row * CHX;
            short8 v = *(const short8*)(WT + (size_t)(n0 + row) * LDW + U_ + ch * 8);
            int byte = row * SX + ((ch * 16) ^ ((row & 7) << 4));
            *(short8*)((char*)WxL + byte) = v;
        }
    }

    const float b0v = bias[n0 + wn + lr];
    const float b1v = bias[n0 + wn + 16 + lr];

    float c_reg[2][2][4];
#pragma unroll
    for (int i = 0; i < 2; i++)
#pragma unroll
        for (int jj = 0; jj < 2; jj++)
#pragma unroll
            for (int r = 0; r < 4; r++) c_reg[i][jj][r] = 0.0f;

    const int rowA0 = m0 + wm + lr, rowA1 = rowA0 + 16;   // global batch rows
    const int rB0 = wn + lr, rB1 = wn + 16 + lr;
    const int sw = (lr & 7) << 4;                          // frag-read swizzle
    const char* WhB0 = (const char*)WhL + rB0 * 1024;
    const char* WhB1 = (const char*)WhL + rB1 * 1024;

    __syncthreads();

    for (int t = 0; t < T_; ++t) {
        const int par = t & 1;
        f32x4 acc[2][2];
#pragma unroll
        for (int i = 0; i < 2; i++)
#pragma unroll
            for (int r = 0; r < 4; r++) { acc[i][0][r] = b0v; acc[i][1][r] = b1v; }

        // ---- x-contribution first (LDS Wx, global x): no dependency ----
        {
            const __hip_bfloat16* X0 = xin + ((size_t)t * B_ + rowA0) * DIN + lq * 8;
            const __hip_bfloat16* X1 = xin + ((size_t)t * B_ + rowA1) * DIN + lq * 8;
#pragma unroll
            for (int k0 = 0; k0 < DIN; k0 += 32) {
                short8 a0 = *(const short8*)(X0 + k0);
                short8 a1 = *(const short8*)(X1 + k0);
                int off = (k0 + lq * 8) * 2;
                short8 bb0 = *(const short8*)((const char*)WxL + rB0 * SX + (off ^ sw));
                short8 bb1 = *(const short8*)((const char*)WxL + rB1 * SX + (off ^ sw));
                acc[0][0] = __builtin_amdgcn_mfma_f32_16x16x32_bf16(a0, bb0, acc[0][0], 0, 0, 0);
                acc[0][1] = __builtin_amdgcn_mfma_f32_16x16x32_bf16(a0, bb1, acc[0][1], 0, 0, 0);
                acc[1][0] = __builtin_amdgcn_mfma_f32_16x16x32_bf16(a1, bb0, acc[1][0], 0, 0, 0);
                acc[1][1] = __builtin_amdgcn_mfma_f32_16x16x32_bf16(a1, bb1, acc[1][1], 0, 0, 0);
            }
        }

        if (t > 0) {
            // ---- per-wave flag snapshot: lanes 0..31 read the 32 flags ----
            unsigned fv = 0xFFFFFFFFu;
            if (l < 32)
                fv = __hip_atomic_load(gflags + l * 16, __ATOMIC_RELAXED, __HIP_MEMORY_SCOPE_AGENT);
            ull rdy = __ballot(fv >= (unsigned)t);

            const __hip_bfloat16* H0 = hs + ((size_t)(t - 1) * B_ + rowA0) * U_ + lq * 8;
            const __hip_bfloat16* H1 = hs + ((size_t)(t - 1) * B_ + rowA1) * U_ + lq * 8;

            // ---- arrival-ordered: two K-halves; per k0-iter poll only the 2
            //      owning producers (usually ready), load A-frags direct from
            //      local L2 into regs (8 iters in flight), then MFMA chunk ----
#pragma unroll
            for (int half = 0; half < 2; ++half) {
                short8 bufA[8], bufB[8];
#pragma unroll
                for (int pp = 0; pp < 8; ++pp) {
                    int itk = half * 8 + pp;               // k0 = itk*32
                    if (((rdy >> (2 * itk)) & 3ull) != 3ull) {
                        const unsigned* f0 = gflags + (2 * itk) * 16;
                        const unsigned* f1 = gflags + (2 * itk + 1) * 16;
                        while (__hip_atomic_load(f0, __ATOMIC_RELAXED, __HIP_MEMORY_SCOPE_AGENT) < (unsigned)t ||
                               __hip_atomic_load(f1, __ATOMIC_RELAXED, __HIP_MEMORY_SCOPE_AGENT) < (unsigned)t)
                            __builtin_amdgcn_s_sleep(1);
                        asm volatile("" ::: "memory");
                    }
                    bufA[pp] = *(const short8*)(H0 + itk * 32);
                    bufB[pp] = *(const short8*)(H1 + itk * 32);
                }
#pragma unroll
                for (int pp = 0; pp < 8; ++pp) {
                    int k0 = (half * 8 + pp) * 32;
                    int off = (k0 + lq * 8) * 2;
                    short8 bb0 = *(const short8*)(WhB0 + (off ^ sw));
                    short8 bb1 = *(const short8*)(WhB1 + (off ^ sw));
                    acc[0][0] = __builtin_amdgcn_mfma_f32_16x16x32_bf16(bufA[pp], bb0, acc[0][0], 0, 0, 0);
                    acc[0][1] = __builtin_amdgcn_mfma_f32_16x16x32_bf16(bufA[pp], bb1, acc[0][1], 0, 0, 0);
                    acc[1][0] = __builtin_amdgcn_mfma_f32_16x16x32_bf16(bufB[pp], bb0, acc[1][0], 0, 0, 0);
                    acc[1][1] = __builtin_amdgcn_mfma_f32_16x16x32_bf16(bufB[pp], bb1, acc[1][1], 0, 0, 0);
                }
            }
        }

        // ---- gates: one exp + one rcp per value; writers update c, stage h
        //      into the parity buffer (other parity still readable by wave0) ----
#pragma unroll
        for (int i = 0; i < 2; i++)
#pragma unroll
            for (int jj = 0; jj < 2; jj++) {
#pragma unroll
                for (int r = 0; r < 4; r++) {
                    float v = acc[i][jj][r];
                    float e = __expf((gate == 2) ? -2.0f * v : -v);
                    float s = 1.0f / (1.0f + e);
                    acc[i][jj][r] = (gate == 2) ? 2.0f * s - 1.0f : s;
                }
#pragma unroll
                for (int r = 0; r < 4; r++) {
                    float nv = acc[i][jj][r];          // i-gate on writer lanes
                    float f1 = __shfl_xor(nv, 1);      // f
                    float f2 = __shfl_xor(nv, 2);      // c~ (tanh'd)
                    float f3 = __shfl_xor(nv, 3);      // o
                    if (gate == 0) {
                        float cn = f1 * c_reg[i][jj][r] + nv * f2;
                        c_reg[i][jj][r] = cn;
                        float hv = f3 * tanhf_(cn);
                        int lrow = wm + i * 16 + lq * 4 + r;          // 0..63
                        int lu = (wn + jj * 16 + lr) >> 2;            // 0..15
                        hstage[par][lrow * 16 + lu] = __float2bfloat16(hv);
                    }
                }
            }

        __syncthreads();   // hstage[par] complete (single barrier per step)

        // ---- wave0 tail: 64 lanes x 32B contiguous stores to local L2, own
        //      vmcnt ack, MALL signal. Waves 1-3 run ahead into t+1 (they
        //      write hstage[par^1], never hstage[par] before next barrier). ----
        if (w == 0) {
            short8 X = *(const short8*)(&hstage[par][l * 16]);
            short8 Y = *(const short8*)(&hstage[par][l * 16 + 8]);
            __hip_bfloat16* dst = hs + ((size_t)t * B_ + m0 + l) * U_ + j * 16;
            *(short8*)dst = X;
            *(short8*)(dst + 8) = Y;
            if (t < T_ - 1) {
                asm volatile("s_waitcnt vmcnt(0)" ::: "memory");   // stores acked in L2
                if (l == 0)
                    __hip_atomic_store(myflag, (unsigned)(t + 1), __ATOMIC_RELAXED, __HIP_MEMORY_SCOPE_AGENT);
            }
        }
    }
}

// ---------------------------------------------------------------------------
// dense: out[M,N] = A[M,K](bf16,[T][B] rows) @ WT[N,K](bf16) + bias ;
// fp32 out written in harness [B][T] row order.
// ---------------------------------------------------------------------------
__global__ __launch_bounds__(256) void gemm_bias(
    const __hip_bfloat16* __restrict__ A, const __hip_bfloat16* __restrict__ WT,
    const float* __restrict__ bias, float* __restrict__ out, int K, int N) {
    const int m0 = blockIdx.x * 128, n0 = blockIdx.y * 64;
    const int tid = threadIdx.x, w = tid >> 6, l = tid & 63, lr = l & 15, lq = l >> 4;
    const int wm = w * 32;

    f32x4 acc[2][4];
#pragma unroll
    for (int jj = 0; jj < 4; jj++) {
        float bv = bias[n0 + jj * 16 + lr];
#pragma unroll
        for (int i = 0; i < 2; i++)
#pragma unroll
            for (int r = 0; r < 4; r++) acc[i][jj][r] = bv;
    }
    for (int k0 = 0; k0 < K; k0 += 32) {
        short8 a[2], b[4];
#pragma unroll
        for (int i = 0; i < 2; i++)
            a[i] = *(const short8*)(A + (size_t)(m0 + wm + i * 16 + lr) * K + k0 + lq * 8);
#pragma unroll
        for (int jj = 0; jj < 4; jj++)
            b[jj] = *(const short8*)(WT + (size_t)(n0 + jj * 16 + lr) * K + k0 + lq * 8);
#pragma unroll
        for (int i = 0; i < 2; i++)
#pragma unroll
            for (int jj = 0; jj < 4; jj++)
                acc[i][jj] = __builtin_amdgcn_mfma_f32_16x16x32_bf16(a[i], b[jj], acc[i][jj], 0, 0, 0);
    }
#pragma unroll
    for (int i = 0; i < 2; i++)
#pragma unroll
        for (int jj = 0; jj < 4; jj++)
#pragma unroll
            for (int r = 0; r < 4; r++) {
                int ra = m0 + wm + i * 16 + lq * 4 + r;     // = t*512 + b
                int rh = (ra & 511) * T_ + (ra >> 9);       // = b*T + t
                out[(size_t)rh * N + n0 + jj * 16 + lr] = acc[i][jj][r];
            }
}

// ---------------------------------------------------------------------------
// reparameterize: z = zm + exp(0.5*zlv)*eps (harness [B][T][Z] order);
// also emits exp(zlv) and bf16 z in [T][B][Z] layout for the decoder.
// ---------------------------------------------------------------------------
__global__ void reparam(const float* __restrict__ zm, const float* __restrict__ zlv,
                        const float* __restrict__ eps, float* __restrict__ z,
                        float* __restrict__ ezlv, __hip_bfloat16* __restrict__ zb, int n) {
    int i = blockIdx.x * 256 + threadIdx.x;
    if (i >= n) return;
    float m = zm[i], lv = zlv[i];
    float zi = m + expf(0.5f * lv) * eps[i];
    z[i] = zi;
    ezlv[i] = expf(lv);
    int b = i >> 13;                       // /(T*Z)=8192
    int rem = i & 8191;
    int t = rem >> 6, zc = rem & 63;       // Z=64
    zb[(((size_t)t << 9) + b) * Z_ + zc] = __float2bfloat16(zi);
}

// ---------------------------------------------------------------------------

extern "C" void kernel_launch(void* const* d_in, const int* in_sizes, int n_in,
                              void* d_out, int out_size, void* d_ws, size_t ws_size,
                              hipStream_t stream) {
    const float* x    = (const float*)d_in[0];
    const float* eps  = (const float*)d_in[1];
    const float* e0Wx = (const float*)d_in[2];
    const float* e0Wh = (const float*)d_in[3];
    const float* e0b  = (const float*)d_in[4];
    const float* e1Wx = (const float*)d_in[5];
    const float* e1Wh = (const float*)d_in[6];
    const float* e1b  = (const float*)d_in[7];
    const float* d0Wx = (const float*)d_in[8];
    const float* d0Wh = (const float*)d_in[9];
    const float* d0b  = (const float*)d_in[10];
    const float* d1Wx = (const float*)d_in[11];
    const float* d1Wh = (const float*)d_in[12];
    const float* d1b  = (const float*)d_in[13];
    const float* Wm   = (const float*)d_in[14];
    const float* bm   = (const float*)d_in[15];
    const float* Wv   = (const float*)d_in[16];
    const float* bv   = (const float*)d_in[17];
    const float* Wo   = (const float*)d_in[18];
    const float* bo   = (const float*)d_in[19];
    float* out = (float*)d_out;

    char* ws = (char*)d_ws;
    size_t off = 0;
    auto alloc = [&](size_t bytes) -> char* {
        off = (off + 255) & ~(size_t)255;
        char* p = ws + off;
        off += bytes;
        return p;
    };
    __hip_bfloat16* hsA  = (__hip_bfloat16*)alloc((size_t)B_ * T_ * U_ * 2); // 64MB, [T][B][U]
    __hip_bfloat16* hsB  = (__hip_bfloat16*)alloc((size_t)B_ * T_ * U_ * 2); // 64MB, [T][B][U]
    __hip_bfloat16* xb   = (__hip_bfloat16*)alloc((size_t)B_ * T_ * D_ * 2); // 16MB, [T][B][D]
    __hip_bfloat16* zb   = (__hip_bfloat16*)alloc((size_t)B_ * T_ * Z_ * 2); //  8MB, [T][B][Z]
    __hip_bfloat16* WTe0 = (__hip_bfloat16*)alloc((size_t)G4_ * (U_ + D_) * 2);
    __hip_bfloat16* WTe1 = (__hip_bfloat16*)alloc((size_t)G4_ * (U_ + U_) * 2);
    __hip_bfloat16* WTd0 = (__hip_bfloat16*)alloc((size_t)G4_ * (U_ + Z_) * 2);
    __hip_bfloat16* WTd1 = (__hip_bfloat16*)alloc((size_t)G4_ * (U_ + U_) * 2);
    __hip_bfloat16* WmT  = (__hip_bfloat16*)alloc((size_t)Z_ * U_ * 2);
    __hip_bfloat16* WvT  = (__hip_bfloat16*)alloc((size_t)Z_ * U_ * 2);
    __hip_bfloat16* WoT  = (__hip_bfloat16*)alloc((size_t)D_ * U_ * 2);
    float* be0 = (float*)alloc(G4_ * 4);
    float* be1 = (float*)alloc(G4_ * 4);
    float* bd0 = (float*)alloc(G4_ * 4);
    float* bd1 = (float*)alloc(G4_ * 4);
    // per-layer ctrl: [8 roster][pad->64][MALL flags 4096] u32
    const int CTRLW = 64 + 4096;
    unsigned* ctrl = (unsigned*)alloc((size_t)4 * CTRLW * sizeof(unsigned));

    hipMemsetAsync(ctrl, 0, (size_t)4 * CTRLW * sizeof(unsigned), stream);

    // ---- prep: bf16 conversions + weight transpose/permutes ----
    convert_transpose<<<(B_ * T_ * D_ + 255) / 256, 256, 0, stream>>>(x, xb);

    auto cw = [&](const float* src, __hip_bfloat16* dst, int K, int Nrows, int Nsrc, int ldd, int koff, int perm) {
        conv_weight<<<(K * Nrows + 255) / 256, 256, 0, stream>>>(src, dst, K, Nrows, Nsrc, ldd, koff, perm);
    };
    cw(e0Wh, WTe0, U_, G4_, G4_, U_ + D_, 0, 1);
    cw(e0Wx, WTe0, D_, G4_, G4_, U_ + D_, U_, 1);
    cw(e1Wh, WTe1, U_, G4_, G4_, U_ + U_, 0, 1);
    cw(e1Wx, WTe1, U_, G4_, G4_, U_ + U_, U_, 1);
    cw(d0Wh, WTd0, U_, G4_, G4_, U_ + Z_, 0, 1);
    cw(d0Wx, WTd0, Z_, G4_, G4_, U_ + Z_, U_, 1);
    cw(d1Wh, WTd1, U_, G4_, G4_, U_ + U_, 0, 1);
    cw(d1Wx, WTd1, U_, G4_, G4_, U_ + U_, U_, 1);
    cw(Wm, WmT, U_, Z_, Z_, U_, 0, 0);
    cw(Wv, WvT, U_, Z_, Z_, U_, 0, 0);
    cw(Wo, WoT, U_, D_, D_, U_, 0, 0);
    conv_bias<<<G4_ / 256, 256, 0, stream>>>(e0b, be0);
    conv_bias<<<G4_ / 256, 256, 0, stream>>>(e1b, be1);
    conv_bias<<<G4_ / 256, 256, 0, stream>>>(d0b, bd0);
    conv_bias<<<G4_ / 256, 256, 0, stream>>>(d1b, bd1);

    // ---- encoder (persistent layers) ----
    lstm_layer_persist<D_><<<256, 256, 0, stream>>>(hsA, xb, WTe0, be0, ctrl + 0 * CTRLW);
    lstm_layer_persist<U_><<<256, 256, 0, stream>>>(hsB, hsA, WTe1, be1, ctrl + 1 * CTRLW);

    // ---- latent heads + reparameterize ----
    const size_t oRecon = 0;
    const size_t oE   = (size_t)B_ * T_ * D_;
    const size_t oZm  = oE + (size_t)B_ * T_ * Z_;
    const size_t oZlv = oZm + (size_t)B_ * T_ * Z_;
    const size_t oZ   = oZlv + (size_t)B_ * T_ * Z_;

    gemm_bias<<<dim3(B_ * T_ / 128, Z_ / 64), 256, 0, stream>>>(hsB, WmT, bm, out + oZm, U_, Z_);
    gemm_bias<<<dim3(B_ * T_ / 128, Z_ / 64), 256, 0, stream>>>(hsB, WvT, bv, out + oZlv, U_, Z_);
    reparam<<<(B_ * T_ * Z_ + 255) / 256, 256, 0, stream>>>(out + oZm, out + oZlv, eps,
                                                            out + oZ, out + oE, zb, B_ * T_ * Z_);

    // ---- decoder (persistent layers) ----
    lstm_layer_persist<Z_><<<256, 256, 0, stream>>>(hsA, zb, WTd0, bd0, ctrl + 2 * CTRLW);
    lstm_layer_persist<U_><<<256, 256, 0, stream>>>(hsB, hsA, WTd1, bd1, ctrl + 3 * CTRLW);

    // ---- output dense ----
    gemm_bias<<<dim3(B_ * T_ / 128, D_ / 64), 256, 0, stream>>>(hsB, WoT, bo, out + oRecon, U_, D_);
}

// Round 18
// 5011.160 us; speedup vs baseline: 1.0210x; 1.0210x over previous
//
#include <hip/hip_runtime.h>
#include <hip/hip_bf16.h>

// C_VAE_NET: 2-layer LSTM encoder -> reparam -> 2-layer LSTM decoder -> dense.
// B=512, T=128, D=128, Z=64, U=512, gates 4U=2048.
// Round 17: R15 + speculative per-lane h-burst.
//  - lane l's 16 stage-chunks all come from producer p=l>>1 (ci&63==l).
//    At step start each lane snapshots flag[p]; if ready (common case) it
//    issues its 16 h-loads BEFORE the x-phase -> L2 latency hides under the
//    x-MFMAs. Stragglers poll+load after the x-phase. No wait-for-all poll
//    phase, no poll barrier (2 barriers/step).
//  - everything else identical to R15: XCD roster, plain-store/plain-load h
//    via XCD-local L2, swizzled LDS h-MFMA, MALL flags + s_sleep(1), Wh/Wx
//    LDS-resident, c-state in regs, wave0 store+vmcnt+signal tail.

#define B_  512
#define T_  128
#define D_  128
#define Z_  64
#define U_  512
#define G4_ 2048

typedef __attribute__((ext_vector_type(8))) short short8; // 8 x bf16
typedef __attribute__((ext_vector_type(4))) float f32x4;
typedef unsigned long long ull;

__device__ __forceinline__ float tanhf_(float x){ return 2.0f / (1.0f + __expf(-2.0f * x)) - 1.0f; }

// ---------------------------------------------------------------------------
// prep kernels
// ---------------------------------------------------------------------------

// x [B][T][D] fp32 -> xb [T][B][D] bf16
__global__ void convert_transpose(const float* __restrict__ src, __hip_bfloat16* __restrict__ dst) {
    int i = blockIdx.x * 256 + threadIdx.x;          // dst-linear over T*B*D
    if (i >= B_ * T_ * D_) return;
    int t = i >> 16;                                  // /(B*D)=65536
    int rem = i & 65535;
    int b = rem >> 7, d = rem & 127;                  // D=128
    dst[i] = __float2bfloat16(src[((size_t)b * T_ + t) * D_ + d]);
}

// dst[n][koff+k] = bf16(src[k][pcol(n)]) ; src is [K][Nsrc] row-major fp32.
// perm: pcol = (n&3)*512 + (n>>2)  (gate-interleave i,f,c,o per unit), else n.
__global__ void conv_weight(const float* __restrict__ src, __hip_bfloat16* __restrict__ dst,
                            int K, int Nrows, int Nsrc, int ldd, int koff, int perm) {
    int idx = blockIdx.x * 256 + threadIdx.x;
    if (idx >= K * Nrows) return;
    int n = idx / K, k = idx - n * K;
    int pc = perm ? ((n & 3) * 512 + (n >> 2)) : n;
    dst[(size_t)n * ldd + koff + k] = __float2bfloat16(src[(size_t)k * Nsrc + pc]);
}

__global__ void conv_bias(const float* __restrict__ src, float* __restrict__ dst) {
    int n = blockIdx.x * 256 + threadIdx.x;
    if (n < G4_) dst[n] = src[(n & 3) * 512 + (n >> 2)];
}

// ---------------------------------------------------------------------------
// persistent LSTM layer, XCD-local groups.
// hs  : [T][B][U] bf16 (wave0 contiguous plain stores -> local L2 write-back)
// xin : [T][B][DIN] bf16 (plain cached loads)
// WT  : [2048][512+DIN] bf16, row n = permuted gate col; cols = [Wh | Wx]
// ctrl: per-layer [8 roster][pad->64][MALL flags 8*32*16], pre-zeroed
// grid 256 blocks x 256 thr; big LDS => 1 block/CU => 32 blocks/XCD.
// ---------------------------------------------------------------------------
template <int DIN>
__global__ __launch_bounds__(256, 1) void lstm_layer_persist(
    __hip_bfloat16* __restrict__ hs,
    const __hip_bfloat16* __restrict__ xin,
    const __hip_bfloat16* __restrict__ WT,
    const float* __restrict__ bias,
    unsigned* __restrict__ ctrl) {
    constexpr bool WX_LDS = (DIN <= 128);
    constexpr int LDW = U_ + DIN;
    constexpr int SX = DIN * 2;                 // Wx LDS row byte stride
    __shared__ __hip_bfloat16 WhL[64 * 512];    // 64KB, swizzled
    __shared__ __hip_bfloat16 hL[64 * 512];     // 64KB, swizzled
    __shared__ __hip_bfloat16 WxL[WX_LDS ? 64 * DIN : 64];
    __shared__ __hip_bfloat16 hstage[64 * 16];  // 2KB
    __shared__ unsigned sj;

    const int tid = threadIdx.x;
    const int w = tid >> 6, l = tid & 63, lr = l & 15, lq = l >> 4;
    const int wm = (w >> 1) * 32, wn = (w & 1) * 32;
    const int gate = l & 3;
    const int p = l >> 1;                       // this lane's stage producer

    // ---- physical XCD id -> group; roster slot -> column tile ----
    unsigned xcc;
    asm volatile("s_getreg_b32 %0, hwreg(HW_REG_XCC_ID)" : "=s"(xcc));
    const int g = (int)(xcc & 7);
    if (tid == 0)
        sj = __hip_atomic_fetch_add(ctrl + g, 1u, __ATOMIC_RELAXED, __HIP_MEMORY_SCOPE_AGENT);
    __syncthreads();
    const int j = (int)(sj & 31);
    const int m0 = g * 64, n0 = j * 64;
    unsigned* gflags = ctrl + 64 + g * (32 * 16);
    unsigned* myflag = gflags + j * 16;

    // ---- stage Wh (and Wx if small) into LDS, XOR-swizzled ----
    for (int idx = tid; idx < 64 * 64; idx += 256) {
        int row = idx >> 6, ch = idx & 63;
        short8 v = *(const short8*)(WT + (size_t)(n0 + row) * LDW + ch * 8);
        int byte = row * 1024 + ((ch * 16) ^ ((row & 7) << 4));
        *(short8*)((char*)WhL + byte) = v;
    }
    if constexpr (WX_LDS) {
        constexpr int CHX = DIN / 8;
        for (int idx = tid; idx < 64 * CHX; idx += 256) {
            int row = idx / CHX, ch = idx - row * CHX;
            short8 v = *(const short8*)(WT + (size_t)(n0 + row) * LDW + U_ + ch * 8);
            int byte = row * SX + ((ch * 16) ^ ((row & 7) << 4));
            *(short8*)((char*)WxL + byte) = v;
        }
    }

    const float b0v = bias[n0 + wn + lr];
    const float b1v = bias[n0 + wn + 16 + lr];

    float c_reg[2][2][4];
#pragma unroll
    for (int i = 0; i < 2; i++)
#pragma unroll
        for (int jj = 0; jj < 2; jj++)
#pragma unroll
            for (int r = 0; r < 4; r++) c_reg[i][jj][r] = 0.0f;

    const int rowA0 = m0 + wm + lr, rowA1 = rowA0 + 16;   // global batch rows
    const int rB0 = wn + lr, rB1 = wn + 16 + lr;
    const int sw = (lr & 7) << 4;                          // frag-read swizzle
    const char* WhB0 = (const char*)WhL + rB0 * 1024;
    const char* WhB1 = (const char*)WhL + rB1 * 1024;
    const char* hA0  = (const char*)hL + (wm + lr) * 1024;
    const char* hA1  = (const char*)hL + (wm + 16 + lr) * 1024;

    __syncthreads();

    for (int t = 0; t < T_; ++t) {
        f32x4 acc[2][2];
#pragma unroll
        for (int i = 0; i < 2; i++)
#pragma unroll
            for (int r = 0; r < 4; r++) { acc[i][0][r] = b0v; acc[i][1][r] = b1v; }

        // ---- speculative per-lane h-burst: if this lane's producer already
        //      signaled, issue its 16 h-loads NOW (hide under x-phase) ----
        short8 buf[16];
        bool rdy = false;
        const short8* hsrc = (const short8*)(hs + ((size_t)(t - 1) * B_ + m0) * U_);
        if (t > 0) {
            unsigned myf = __hip_atomic_load(gflags + p * 16, __ATOMIC_RELAXED, __HIP_MEMORY_SCOPE_AGENT);
            rdy = (myf >= (unsigned)t);
            if (rdy) {
                asm volatile("" ::: "memory");
#pragma unroll
                for (int c = 0; c < 16; ++c) buf[c] = hsrc[c * 256 + tid];
            }
        }

        // ---- x-contribution (overlaps speculative loads' latency) ----
        {
            const __hip_bfloat16* X0 = xin + ((size_t)t * B_ + rowA0) * DIN + lq * 8;
            const __hip_bfloat16* X1 = xin + ((size_t)t * B_ + rowA1) * DIN + lq * 8;
#pragma unroll
            for (int k0 = 0; k0 < DIN; k0 += 32) {
                short8 a0 = *(const short8*)(X0 + k0);
                short8 a1 = *(const short8*)(X1 + k0);
                short8 bb0, bb1;
                if constexpr (WX_LDS) {
                    int off = (k0 + lq * 8) * 2;
                    bb0 = *(const short8*)((const char*)WxL + rB0 * SX + (off ^ sw));
                    bb1 = *(const short8*)((const char*)WxL + rB1 * SX + (off ^ sw));
                } else {
                    bb0 = *(const short8*)(WT + (size_t)(n0 + rB0) * LDW + U_ + k0 + lq * 8);
                    bb1 = *(const short8*)(WT + (size_t)(n0 + rB1) * LDW + U_ + k0 + lq * 8);
                }
                acc[0][0] = __builtin_amdgcn_mfma_f32_16x16x32_bf16(a0, bb0, acc[0][0], 0, 0, 0);
                acc[0][1] = __builtin_amdgcn_mfma_f32_16x16x32_bf16(a0, bb1, acc[0][1], 0, 0, 0);
                acc[1][0] = __builtin_amdgcn_mfma_f32_16x16x32_bf16(a1, bb0, acc[1][0], 0, 0, 0);
                acc[1][1] = __builtin_amdgcn_mfma_f32_16x16x32_bf16(a1, bb1, acc[1][1], 0, 0, 0);
            }
        }

        if (t > 0) {
            // ---- straggler lanes: poll own producer, then load ----
            if (!rdy) {
                const unsigned* f = gflags + p * 16;
                while (__hip_atomic_load(f, __ATOMIC_RELAXED, __HIP_MEMORY_SCOPE_AGENT) < (unsigned)t)
                    __builtin_amdgcn_s_sleep(1);
                asm volatile("" ::: "memory");
#pragma unroll
                for (int c = 0; c < 16; ++c) buf[c] = hsrc[c * 256 + tid];
            }

            // ---- swizzled ds_writes (ch == l for all chunks) ----
#pragma unroll
            for (int c = 0; c < 16; ++c) {
                int row = (c * 256 + tid) >> 6;
                int byte = row * 1024 + ((l * 16) ^ ((row & 7) << 4));
                *(short8*)((char*)hL + byte) = buf[c];
            }
            __syncthreads();   // hL complete

            // ---- h-contribution from LDS (swizzled, lgkm-pipelined) ----
#pragma unroll 8
            for (int k0 = 0; k0 < U_; k0 += 32) {
                int off = (k0 + lq * 8) * 2;
                short8 a0 = *(const short8*)(hA0 + (off ^ sw));
                short8 a1 = *(const short8*)(hA1 + (off ^ sw));
                short8 bb0 = *(const short8*)(WhB0 + (off ^ sw));
                short8 bb1 = *(const short8*)(WhB1 + (off ^ sw));
                acc[0][0] = __builtin_amdgcn_mfma_f32_16x16x32_bf16(a0, bb0, acc[0][0], 0, 0, 0);
                acc[0][1] = __builtin_amdgcn_mfma_f32_16x16x32_bf16(a0, bb1, acc[0][1], 0, 0, 0);
                acc[1][0] = __builtin_amdgcn_mfma_f32_16x16x32_bf16(a1, bb0, acc[1][0], 0, 0, 0);
                acc[1][1] = __builtin_amdgcn_mfma_f32_16x16x32_bf16(a1, bb1, acc[1][1], 0, 0, 0);
            }
        }

        // ---- gates: one exp + one rcp per value; writers update c, stage h ----
#pragma unroll
        for (int i = 0; i < 2; i++)
#pragma unroll
            for (int jj = 0; jj < 2; jj++) {
#pragma unroll
                for (int r = 0; r < 4; r++) {
                    float v = acc[i][jj][r];
                    float e = __expf((gate == 2) ? -2.0f * v : -v);
                    float s = 1.0f / (1.0f + e);
                    acc[i][jj][r] = (gate == 2) ? 2.0f * s - 1.0f : s;
                }
#pragma unroll
                for (int r = 0; r < 4; r++) {
                    float nv = acc[i][jj][r];          // i-gate on writer lanes
                    float f1 = __shfl_xor(nv, 1);      // f
                    float f2 = __shfl_xor(nv, 2);      // c~ (tanh'd)
                    float f3 = __shfl_xor(nv, 3);      // o
                    if (gate == 0) {
                        float cn = f1 * c_reg[i][jj][r] + nv * f2;
                        c_reg[i][jj][r] = cn;
                        float hv = f3 * tanhf_(cn);
                        int lrow = wm + i * 16 + lq * 4 + r;          // 0..63
                        int lu = (wn + jj * 16 + lr) >> 2;            // 0..15
                        hstage[lrow * 16 + lu] = __float2bfloat16(hv);
                    }
                }
            }

        __syncthreads();   // hstage complete; hL reads of this step done

        // ---- wave0 tail: 64 lanes x 32B contiguous stores to local L2, own
        //      vmcnt ack, MALL signal. Waves 1-3 run ahead into t+1; hL and
        //      hstage reuse guarded by t+1's two barriers. ----
        if (w == 0) {
            short8 X = *(const short8*)(hstage + l * 16);
            short8 Y = *(const short8*)(hstage + l * 16 + 8);
            __hip_bfloat16* dst = hs + ((size_t)t * B_ + m0 + l) * U_ + j * 16;
            *(short8*)dst = X;
            *(short8*)(dst + 8) = Y;
            if (t < T_ - 1) {
                asm volatile("s_waitcnt vmcnt(0)" ::: "memory");   // stores acked in L2
                if (l == 0)
                    __hip_atomic_store(myflag, (unsigned)(t + 1), __ATOMIC_RELAXED, __HIP_MEMORY_SCOPE_AGENT);
            }
        }
    }
}

// ---------------------------------------------------------------------------
// dense: out[M,N] = A[M,K](bf16,[T][B] rows) @ WT[N,K](bf16) + bias ;
// fp32 out written in harness [B][T] row order.
// ---------------------------------------------------------------------------
__global__ __launch_bounds__(256) void gemm_bias(
    const __hip_bfloat16* __restrict__ A, const __hip_bfloat16* __restrict__ WT,
    const float* __restrict__ bias, float* __restrict__ out, int K, int N) {
    const int m0 = blockIdx.x * 128, n0 = blockIdx.y * 64;
    const int tid = threadIdx.x, w = tid >> 6, l = tid & 63, lr = l & 15, lq = l >> 4;
    const int wm = w * 32;

    f32x4 acc[2][4];
#pragma unroll
    for (int jj = 0; jj < 4; jj++) {
        float bv = bias[n0 + jj * 16 + lr];
#pragma unroll
        for (int i = 0; i < 2; i++)
#pragma unroll
            for (int r = 0; r < 4; r++) acc[i][jj][r] = bv;
    }
    for (int k0 = 0; k0 < K; k0 += 32) {
        short8 a[2], b[4];
#pragma unroll
        for (int i = 0; i < 2; i++)
            a[i] = *(const short8*)(A + (size_t)(m0 + wm + i * 16 + lr) * K + k0 + lq * 8);
#pragma unroll
        for (int jj = 0; jj < 4; jj++)
            b[jj] = *(const short8*)(WT + (size_t)(n0 + jj * 16 + lr) * K + k0 + lq * 8);
#pragma unroll
        for (int i = 0; i < 2; i++)
#pragma unroll
            for (int jj = 0; jj < 4; jj++)
                acc[i][jj] = __builtin_amdgcn_mfma_f32_16x16x32_bf16(a[i], b[jj], acc[i][jj], 0, 0, 0);
    }
#pragma unroll
    for (int i = 0; i < 2; i++)
#pragma unroll
        for (int jj = 0; jj < 4; jj++)
#pragma unroll
            for (int r = 0; r < 4; r++) {
                int ra = m0 + wm + i * 16 + lq * 4 + r;     // = t*512 + b
                int rh = (ra & 511) * T_ + (ra >> 9);       // = b*T + t
                out[(size_t)rh * N + n0 + jj * 16 + lr] = acc[i][jj][r];
            }
}

// ---------------------------------------------------------------------------
// reparameterize: z = zm + exp(0.5*zlv)*eps (harness [B][T][Z] order);
// also emits exp(zlv) and bf16 z in [T][B][Z] layout for the decoder.
// ---------------------------------------------------------------------------
__global__ void reparam(const float* __restrict__ zm, const float* __restrict__ zlv,
                        const float* __restrict__ eps, float* __restrict__ z,
                        float* __restrict__ ezlv, __hip_bfloat16* __restrict__ zb, int n) {
    int i = blockIdx.x * 256 + threadIdx.x;
    if (i >= n) return;
    float m = zm[i], lv = zlv[i];
    float zi = m + expf(0.5f * lv) * eps[i];
    z[i] = zi;
    ezlv[i] = expf(lv);
    int b = i >> 13;                       // /(T*Z)=8192
    int rem = i & 8191;
    int t = rem >> 6, zc = rem & 63;       // Z=64
    zb[(((size_t)t << 9) + b) * Z_ + zc] = __float2bfloat16(zi);
}

// ---------------------------------------------------------------------------

extern "C" void kernel_launch(void* const* d_in, const int* in_sizes, int n_in,
                              void* d_out, int out_size, void* d_ws, size_t ws_size,
                              hipStream_t stream) {
    const float* x    = (const float*)d_in[0];
    const float* eps  = (const float*)d_in[1];
    const float* e0Wx = (const float*)d_in[2];
    const float* e0Wh = (const float*)d_in[3];
    const float* e0b  = (const float*)d_in[4];
    const float* e1Wx = (const float*)d_in[5];
    const float* e1Wh = (const float*)d_in[6];
    const float* e1b  = (const float*)d_in[7];
    const float* d0Wx = (const float*)d_in[8];
    const float* d0Wh = (const float*)d_in[9];
    const float* d0b  = (const float*)d_in[10];
    const float* d1Wx = (const float*)d_in[11];
    const float* d1Wh = (const float*)d_in[12];
    const float* d1b  = (const float*)d_in[13];
    const float* Wm   = (const float*)d_in[14];
    const float* bm   = (const float*)d_in[15];
    const float* Wv   = (const float*)d_in[16];
    const float* bv   = (const float*)d_in[17];
    const float* Wo   = (const float*)d_in[18];
    const float* bo   = (const float*)d_in[19];
    float* out = (float*)d_out;

    char* ws = (char*)d_ws;
    size_t off = 0;
    auto alloc = [&](size_t bytes) -> char* {
        off = (off + 255) & ~(size_t)255;
        char* p = ws + off;
        off += bytes;
        return p;
    };
    __hip_bfloat16* hsA  = (__hip_bfloat16*)alloc((size_t)B_ * T_ * U_ * 2); // 64MB, [T][B][U]
    __hip_bfloat16* hsB  = (__hip_bfloat16*)alloc((size_t)B_ * T_ * U_ * 2); // 64MB, [T][B][U]
    __hip_bfloat16* xb   = (__hip_bfloat16*)alloc((size_t)B_ * T_ * D_ * 2); // 16MB, [T][B][D]
    __hip_bfloat16* zb   = (__hip_bfloat16*)alloc((size_t)B_ * T_ * Z_ * 2); //  8MB, [T][B][Z]
    __hip_bfloat16* WTe0 = (__hip_bfloat16*)alloc((size_t)G4_ * (U_ + D_) * 2);
    __hip_bfloat16* WTe1 = (__hip_bfloat16*)alloc((size_t)G4_ * (U_ + U_) * 2);
    __hip_bfloat16* WTd0 = (__hip_bfloat16*)alloc((size_t)G4_ * (U_ + Z_) * 2);
    __hip_bfloat16* WTd1 = (__hip_bfloat16*)alloc((size_t)G4_ * (U_ + U_) * 2);
    __hip_bfloat16* WmT  = (__hip_bfloat16*)alloc((size_t)Z_ * U_ * 2);
    __hip_bfloat16* WvT  = (__hip_bfloat16*)alloc((size_t)Z_ * U_ * 2);
    __hip_bfloat16* WoT  = (__hip_bfloat16*)alloc((size_t)D_ * U_ * 2);
    float* be0 = (float*)alloc(G4_ * 4);
    float* be1 = (float*)alloc(G4_ * 4);
    float* bd0 = (float*)alloc(G4_ * 4);
    float* bd1 = (float*)alloc(G4_ * 4);
    // per-layer ctrl: [8 roster][pad->64][MALL flags 4096] u32
    const int CTRLW = 64 + 4096;
    unsigned* ctrl = (unsigned*)alloc((size_t)4 * CTRLW * sizeof(unsigned));

    hipMemsetAsync(ctrl, 0, (size_t)4 * CTRLW * sizeof(unsigned), stream);

    // ---- prep: bf16 conversions + weight transpose/permutes ----
    convert_transpose<<<(B_ * T_ * D_ + 255) / 256, 256, 0, stream>>>(x, xb);

    auto cw = [&](const float* src, __hip_bfloat16* dst, int K, int Nrows, int Nsrc, int ldd, int koff, int perm) {
        conv_weight<<<(K * Nrows + 255) / 256, 256, 0, stream>>>(src, dst, K, Nrows, Nsrc, ldd, koff, perm);
    };
    cw(e0Wh, WTe0, U_, G4_, G4_, U_ + D_, 0, 1);
    cw(e0Wx, WTe0, D_, G4_, G4_, U_ + D_, U_, 1);
    cw(e1Wh, WTe1, U_, G4_, G4_, U_ + U_, 0, 1);
    cw(e1Wx, WTe1, U_, G4_, G4_, U_ + U_, U_, 1);
    cw(d0Wh, WTd0, U_, G4_, G4_, U_ + Z_, 0, 1);
    cw(d0Wx, WTd0, Z_, G4_, G4_, U_ + Z_, U_, 1);
    cw(d1Wh, WTd1, U_, G4_, G4_, U_ + U_, 0, 1);
    cw(d1Wx, WTd1, U_, G4_, G4_, U_ + U_, U_, 1);
    cw(Wm, WmT, U_, Z_, Z_, U_, 0, 0);
    cw(Wv, WvT, U_, Z_, Z_, U_, 0, 0);
    cw(Wo, WoT, U_, D_, D_, U_, 0, 0);
    conv_bias<<<G4_ / 256, 256, 0, stream>>>(e0b, be0);
    conv_bias<<<G4_ / 256, 256, 0, stream>>>(e1b, be1);
    conv_bias<<<G4_ / 256, 256, 0, stream>>>(d0b, bd0);
    conv_bias<<<G4_ / 256, 256, 0, stream>>>(d1b, bd1);

    // ---- encoder (persistent layers) ----
    lstm_layer_persist<D_><<<256, 256, 0, stream>>>(hsA, xb, WTe0, be0, ctrl + 0 * CTRLW);
    lstm_layer_persist<U_><<<256, 256, 0, stream>>>(hsB, hsA, WTe1, be1, ctrl + 1 * CTRLW);

    // ---- latent heads + reparameterize ----
    const size_t oRecon = 0;
    const size_t oE   = (size_t)B_ * T_ * D_;
    const size_t oZm  = oE + (size_t)B_ * T_ * Z_;
    const size_t oZlv = oZm + (size_t)B_ * T_ * Z_;
    const size_t oZ   = oZlv + (size_t)B_ * T_ * Z_;

    gemm_bias<<<dim3(B_ * T_ / 128, Z_ / 64), 256, 0, stream>>>(hsB, WmT, bm, out + oZm, U_, Z_);
    gemm_bias<<<dim3(B_ * T_ / 128, Z_ / 64), 256, 0, stream>>>(hsB, WvT, bv, out + oZlv, U_, Z_);
    reparam<<<(B_ * T_ * Z_ + 255) / 256, 256, 0, stream>>>(out + oZm, out + oZlv, eps,
                                                            out + oZ, out + oE, zb, B_ * T_ * Z_);

    // ---- decoder (persistent layers) ----
    lstm_layer_persist<Z_><<<256, 256, 0, stream>>>(hsA, zb, WTd0, bd0, ctrl + 2 * CTRLW);
    lstm_layer_persist<U_><<<256, 256, 0, stream>>>(hsB, hsA, WTd1, bd1, ctrl + 3 * CTRLW);

    // ---- output dense ----
    gemm_bias<<<dim3(B_ * T_ / 128, D_ / 64), 256, 0, stream>>>(hsB, WoT, bo, out + oRecon, U_, D_);
}

// Round 19
// 3427.806 us; speedup vs baseline: 1.4927x; 1.4619x over previous
//
#include <hip/hip_runtime.h>
#include <hip/hip_bf16.h>

// C_VAE_NET: 2-layer LSTM encoder -> reparam -> 2-layer LSTM decoder -> dense.
// B=512, T=128, D=128, Z=64, U=512, gates 4U=2048.
// Round 18: R15 structure at 512 threads/block (8 waves => 2 waves/SIMD).
//  - same 64x64 tile; wave tile now 16(M)x32(N) (2 MFMAs/k0/wave);
//    stage loop 8 chunks/thread; gate VALU halved per thread. 2 waves/SIMD
//    lets the CU overlap LDS/exp latency of one wave with the other's MFMAs.
//  - all R15-proven parts: XCD roster, plain-store/plain-load h via XCD-local
//    L2, register-burst stage -> swizzled LDS h-MFMA, MALL flags + s_sleep(1)
//    (wave7 polls), wave0 store+vmcnt+signal tail, Wh/Wx LDS, c-state in regs.

#define B_  512
#define T_  128
#define D_  128
#define Z_  64
#define U_  512
#define G4_ 2048

typedef __attribute__((ext_vector_type(8))) short short8; // 8 x bf16
typedef __attribute__((ext_vector_type(4))) float f32x4;
typedef unsigned long long ull;

__device__ __forceinline__ float tanhf_(float x){ return 2.0f / (1.0f + __expf(-2.0f * x)) - 1.0f; }

// ---------------------------------------------------------------------------
// prep kernels
// ---------------------------------------------------------------------------

// x [B][T][D] fp32 -> xb [T][B][D] bf16
__global__ void convert_transpose(const float* __restrict__ src, __hip_bfloat16* __restrict__ dst) {
    int i = blockIdx.x * 256 + threadIdx.x;          // dst-linear over T*B*D
    if (i >= B_ * T_ * D_) return;
    int t = i >> 16;                                  // /(B*D)=65536
    int rem = i & 65535;
    int b = rem >> 7, d = rem & 127;                  // D=128
    dst[i] = __float2bfloat16(src[((size_t)b * T_ + t) * D_ + d]);
}

// dst[n][koff+k] = bf16(src[k][pcol(n)]) ; src is [K][Nsrc] row-major fp32.
// perm: pcol = (n&3)*512 + (n>>2)  (gate-interleave i,f,c,o per unit), else n.
__global__ void conv_weight(const float* __restrict__ src, __hip_bfloat16* __restrict__ dst,
                            int K, int Nrows, int Nsrc, int ldd, int koff, int perm) {
    int idx = blockIdx.x * 256 + threadIdx.x;
    if (idx >= K * Nrows) return;
    int n = idx / K, k = idx - n * K;
    int pc = perm ? ((n & 3) * 512 + (n >> 2)) : n;
    dst[(size_t)n * ldd + koff + k] = __float2bfloat16(src[(size_t)k * Nsrc + pc]);
}

__global__ void conv_bias(const float* __restrict__ src, float* __restrict__ dst) {
    int n = blockIdx.x * 256 + threadIdx.x;
    if (n < G4_) dst[n] = src[(n & 3) * 512 + (n >> 2)];
}

// ---------------------------------------------------------------------------
// persistent LSTM layer, XCD-local groups, 512 threads (8 waves).
// hs  : [T][B][U] bf16 (wave0 contiguous plain stores -> local L2 write-back)
// xin : [T][B][DIN] bf16 (plain cached loads)
// WT  : [2048][512+DIN] bf16, row n = permuted gate col; cols = [Wh | Wx]
// ctrl: per-layer [8 roster][pad->64][MALL flags 8*32*16], pre-zeroed
// grid 256 blocks x 512 thr; big LDS => 1 block/CU => 32 blocks/XCD.
// wave w: rows wm=(w&3)*16, cols wn=(w>>2)*32 of the 64x64 tile.
// ---------------------------------------------------------------------------
template <int DIN>
__global__ __launch_bounds__(512, 1) void lstm_layer_persist(
    __hip_bfloat16* __restrict__ hs,
    const __hip_bfloat16* __restrict__ xin,
    const __hip_bfloat16* __restrict__ WT,
    const float* __restrict__ bias,
    unsigned* __restrict__ ctrl) {
    constexpr bool WX_LDS = (DIN <= 128);
    constexpr int LDW = U_ + DIN;
    constexpr int SX = DIN * 2;                 // Wx LDS row byte stride
    __shared__ __hip_bfloat16 WhL[64 * 512];    // 64KB, swizzled
    __shared__ __hip_bfloat16 hL[64 * 512];     // 64KB, swizzled
    __shared__ __hip_bfloat16 WxL[WX_LDS ? 64 * DIN : 64];
    __shared__ __hip_bfloat16 hstage[64 * 16];  // 2KB
    __shared__ unsigned sj;

    const int tid = threadIdx.x;
    const int w = tid >> 6, l = tid & 63, lr = l & 15, lq = l >> 4;
    const int wm = (w & 3) * 16, wn = (w >> 2) * 32;
    const int gate = l & 3;

    // ---- physical XCD id -> group; roster slot -> column tile ----
    unsigned xcc;
    asm volatile("s_getreg_b32 %0, hwreg(HW_REG_XCC_ID)" : "=s"(xcc));
    const int g = (int)(xcc & 7);
    if (tid == 0)
        sj = __hip_atomic_fetch_add(ctrl + g, 1u, __ATOMIC_RELAXED, __HIP_MEMORY_SCOPE_AGENT);
    __syncthreads();
    const int j = (int)(sj & 31);
    const int m0 = g * 64, n0 = j * 64;
    unsigned* gflags = ctrl + 64 + g * (32 * 16);
    unsigned* myflag = gflags + j * 16;

    // ---- stage Wh (and Wx if small) into LDS, XOR-swizzled ----
    for (int idx = tid; idx < 64 * 64; idx += 512) {
        int row = idx >> 6, ch = idx & 63;
        short8 v = *(const short8*)(WT + (size_t)(n0 + row) * LDW + ch * 8);
        int byte = row * 1024 + ((ch * 16) ^ ((row & 7) << 4));
        *(short8*)((char*)WhL + byte) = v;
    }
    if constexpr (WX_LDS) {
        constexpr int CHX = DIN / 8;
        for (int idx = tid; idx < 64 * CHX; idx += 512) {
            int row = idx / CHX, ch = idx - row * CHX;
            short8 v = *(const short8*)(WT + (size_t)(n0 + row) * LDW + U_ + ch * 8);
            int byte = row * SX + ((ch * 16) ^ ((row & 7) << 4));
            *(short8*)((char*)WxL + byte) = v;
        }
    }

    const float b0v = bias[n0 + wn + lr];
    const float b1v = bias[n0 + wn + 16 + lr];

    float c_reg[2][4];
#pragma unroll
    for (int jj = 0; jj < 2; jj++)
#pragma unroll
        for (int r = 0; r < 4; r++) c_reg[jj][r] = 0.0f;

    const int rowA0 = m0 + wm + lr;                        // global batch row
    const int rB0 = wn + lr, rB1 = wn + 16 + lr;
    const int sw = (lr & 7) << 4;                          // frag-read swizzle
    const char* WhB0 = (const char*)WhL + rB0 * 1024;
    const char* WhB1 = (const char*)WhL + rB1 * 1024;
    const char* hA0  = (const char*)hL + (wm + lr) * 1024;

    __syncthreads();

    for (int t = 0; t < T_; ++t) {
        f32x4 acc[2];
#pragma unroll
        for (int r = 0; r < 4; r++) { acc[0][r] = b0v; acc[1][r] = b1v; }

        // ---- x-contribution first: independent of peers' step t-1 ----
        {
            const __hip_bfloat16* X0 = xin + ((size_t)t * B_ + rowA0) * DIN + lq * 8;
#pragma unroll
            for (int k0 = 0; k0 < DIN; k0 += 32) {
                short8 a0 = *(const short8*)(X0 + k0);
                short8 bb0, bb1;
                if constexpr (WX_LDS) {
                    int off = (k0 + lq * 8) * 2;
                    bb0 = *(const short8*)((const char*)WxL + rB0 * SX + (off ^ sw));
                    bb1 = *(const short8*)((const char*)WxL + rB1 * SX + (off ^ sw));
                } else {
                    bb0 = *(const short8*)(WT + (size_t)(n0 + rB0) * LDW + U_ + k0 + lq * 8);
                    bb1 = *(const short8*)(WT + (size_t)(n0 + rB1) * LDW + U_ + k0 + lq * 8);
                }
                acc[0] = __builtin_amdgcn_mfma_f32_16x16x32_bf16(a0, bb0, acc[0], 0, 0, 0);
                acc[1] = __builtin_amdgcn_mfma_f32_16x16x32_bf16(a0, bb1, acc[1], 0, 0, 0);
            }
        }

        if (t > 0) {
            // ---- wait: WAVE 7 polls (tail-free wave; wave0's tail overlaps) ----
            if (w == 7 && l < 32) {
                const unsigned* f = gflags + l * 16;
                while (__hip_atomic_load(f, __ATOMIC_RELAXED, __HIP_MEMORY_SCOPE_AGENT) < (unsigned)t)
                    __builtin_amdgcn_s_sleep(1);
            }
            __syncthreads();

            // ---- BURST-stage h(t-1) slab (64KB): 8 plain dwordx4 loads per
            //      thread in flight (local L2), THEN swizzled ds_writes ----
            {
                const short8* hsrc = (const short8*)(hs + ((size_t)(t - 1) * B_ + m0) * U_);
                short8 buf[8];
#pragma unroll
                for (int c = 0; c < 8; ++c) buf[c] = hsrc[c * 512 + tid];
#pragma unroll
                for (int c = 0; c < 8; ++c) {
                    int ci = c * 512 + tid;
                    int row = ci >> 6;                     // ci&63 == l
                    int byte = row * 1024 + ((l * 16) ^ ((row & 7) << 4));
                    *(short8*)((char*)hL + byte) = buf[c];
                }
            }
            __syncthreads();

            // ---- h-contribution from LDS (swizzled, lgkm-pipelined) ----
#pragma unroll 8
            for (int k0 = 0; k0 < U_; k0 += 32) {
                int off = (k0 + lq * 8) * 2;
                short8 a0 = *(const short8*)(hA0 + (off ^ sw));
                short8 bb0 = *(const short8*)(WhB0 + (off ^ sw));
                short8 bb1 = *(const short8*)(WhB1 + (off ^ sw));
                acc[0] = __builtin_amdgcn_mfma_f32_16x16x32_bf16(a0, bb0, acc[0], 0, 0, 0);
                acc[1] = __builtin_amdgcn_mfma_f32_16x16x32_bf16(a0, bb1, acc[1], 0, 0, 0);
            }
        }

        // ---- gates: one exp + one rcp per value; writers update c, stage h ----
#pragma unroll
        for (int jj = 0; jj < 2; jj++) {
#pragma unroll
            for (int r = 0; r < 4; r++) {
                float v = acc[jj][r];
                float e = __expf((gate == 2) ? -2.0f * v : -v);
                float s = 1.0f / (1.0f + e);
                acc[jj][r] = (gate == 2) ? 2.0f * s - 1.0f : s;
            }
#pragma unroll
            for (int r = 0; r < 4; r++) {
                float nv = acc[jj][r];             // i-gate on writer lanes
                float f1 = __shfl_xor(nv, 1);      // f
                float f2 = __shfl_xor(nv, 2);      // c~ (tanh'd)
                float f3 = __shfl_xor(nv, 3);      // o
                if (gate == 0) {
                    float cn = f1 * c_reg[jj][r] + nv * f2;
                    c_reg[jj][r] = cn;
                    float hv = f3 * tanhf_(cn);
                    int lrow = wm + lq * 4 + r;               // 0..63
                    int lu = (wn + jj * 16 + lr) >> 2;        // 0..15
                    hstage[lrow * 16 + lu] = __float2bfloat16(hv);
                }
            }
        }

        __syncthreads();   // hstage complete; hL reads of this step done

        // ---- wave0 tail: 64 lanes x 32B contiguous stores to local L2, own
        //      vmcnt ack, MALL signal. Waves 1-7 run ahead into t+1; hL and
        //      hstage reuse guarded by t+1's two barriers. ----
        if (w == 0) {
            short8 X = *(const short8*)(hstage + l * 16);
            short8 Y = *(const short8*)(hstage + l * 16 + 8);
            __hip_bfloat16* dst = hs + ((size_t)t * B_ + m0 + l) * U_ + j * 16;
            *(short8*)dst = X;
            *(short8*)(dst + 8) = Y;
            if (t < T_ - 1) {
                asm volatile("s_waitcnt vmcnt(0)" ::: "memory");   // stores acked in L2
                if (l == 0)
                    __hip_atomic_store(myflag, (unsigned)(t + 1), __ATOMIC_RELAXED, __HIP_MEMORY_SCOPE_AGENT);
            }
        }
    }
}

// ---------------------------------------------------------------------------
// dense: out[M,N] = A[M,K](bf16,[T][B] rows) @ WT[N,K](bf16) + bias ;
// fp32 out written in harness [B][T] row order.
// ---------------------------------------------------------------------------
__global__ __launch_bounds__(256) void gemm_bias(
    const __hip_bfloat16* __restrict__ A, const __hip_bfloat16* __restrict__ WT,
    const float* __restrict__ bias, float* __restrict__ out, int K, int N) {
    const int m0 = blockIdx.x * 128, n0 = blockIdx.y * 64;
    const int tid = threadIdx.x, w = tid >> 6, l = tid & 63, lr = l & 15, lq = l >> 4;
    const int wm = w * 32;

    f32x4 acc[2][4];
#pragma unroll
    for (int jj = 0; jj < 4; jj++) {
        float bv = bias[n0 + jj * 16 + lr];
#pragma unroll
        for (int i = 0; i < 2; i++)
#pragma unroll
            for (int r = 0; r < 4; r++) acc[i][jj][r] = bv;
    }
    for (int k0 = 0; k0 < K; k0 += 32) {
        short8 a[2], b[4];
#pragma unroll
        for (int i = 0; i < 2; i++)
            a[i] = *(const short8*)(A + (size_t)(m0 + wm + i * 16 + lr) * K + k0 + lq * 8);
#pragma unroll
        for (int jj = 0; jj < 4; jj++)
            b[jj] = *(const short8*)(WT + (size_t)(n0 + jj * 16 + lr) * K + k0 + lq * 8);
#pragma unroll
        for (int i = 0; i < 2; i++)
#pragma unroll
            for (int jj = 0; jj < 4; jj++)
                acc[i][jj] = __builtin_amdgcn_mfma_f32_16x16x32_bf16(a[i], b[jj], acc[i][jj], 0, 0, 0);
    }
#pragma unroll
    for (int i = 0; i < 2; i++)
#pragma unroll
        for (int jj = 0; jj < 4; jj++)
#pragma unroll
            for (int r = 0; r < 4; r++) {
                int ra = m0 + wm + i * 16 + lq * 4 + r;     // = t*512 + b
                int rh = (ra & 511) * T_ + (ra >> 9);       // = b*T + t
                out[(size_t)rh * N + n0 + jj * 16 + lr] = acc[i][jj][r];
            }
}

// ---------------------------------------------------------------------------
// reparameterize: z = zm + exp(0.5*zlv)*eps (harness [B][T][Z] order);
// also emits exp(zlv) and bf16 z in [T][B][Z] layout for the decoder.
// ---------------------------------------------------------------------------
__global__ void reparam(const float* __restrict__ zm, const float* __restrict__ zlv,
                        const float* __restrict__ eps, float* __restrict__ z,
                        float* __restrict__ ezlv, __hip_bfloat16* __restrict__ zb, int n) {
    int i = blockIdx.x * 256 + threadIdx.x;
    if (i >= n) return;
    float m = zm[i], lv = zlv[i];
    float zi = m + expf(0.5f * lv) * eps[i];
    z[i] = zi;
    ezlv[i] = expf(lv);
    int b = i >> 13;                       // /(T*Z)=8192
    int rem = i & 8191;
    int t = rem >> 6, zc = rem & 63;       // Z=64
    zb[(((size_t)t << 9) + b) * Z_ + zc] = __float2bfloat16(zi);
}

// ---------------------------------------------------------------------------

extern "C" void kernel_launch(void* const* d_in, const int* in_sizes, int n_in,
                              void* d_out, int out_size, void* d_ws, size_t ws_size,
                              hipStream_t stream) {
    const float* x    = (const float*)d_in[0];
    const float* eps  = (const float*)d_in[1];
    const float* e0Wx = (const float*)d_in[2];
    const float* e0Wh = (const float*)d_in[3];
    const float* e0b  = (const float*)d_in[4];
    const float* e1Wx = (const float*)d_in[5];
    const float* e1Wh = (const float*)d_in[6];
    const float* e1b  = (const float*)d_in[7];
    const float* d0Wx = (const float*)d_in[8];
    const float* d0Wh = (const float*)d_in[9];
    const float* d0b  = (const float*)d_in[10];
    const float* d1Wx = (const float*)d_in[11];
    const float* d1Wh = (const float*)d_in[12];
    const float* d1b  = (const float*)d_in[13];
    const float* Wm   = (const float*)d_in[14];
    const float* bm   = (const float*)d_in[15];
    const float* Wv   = (const float*)d_in[16];
    const float* bv   = (const float*)d_in[17];
    const float* Wo   = (const float*)d_in[18];
    const float* bo   = (const float*)d_in[19];
    float* out = (float*)d_out;

    char* ws = (char*)d_ws;
    size_t off = 0;
    auto alloc = [&](size_t bytes) -> char* {
        off = (off + 255) & ~(size_t)255;
        char* p = ws + off;
        off += bytes;
        return p;
    };
    __hip_bfloat16* hsA  = (__hip_bfloat16*)alloc((size_t)B_ * T_ * U_ * 2); // 64MB, [T][B][U]
    __hip_bfloat16* hsB  = (__hip_bfloat16*)alloc((size_t)B_ * T_ * U_ * 2); // 64MB, [T][B][U]
    __hip_bfloat16* xb   = (__hip_bfloat16*)alloc((size_t)B_ * T_ * D_ * 2); // 16MB, [T][B][D]
    __hip_bfloat16* zb   = (__hip_bfloat16*)alloc((size_t)B_ * T_ * Z_ * 2); //  8MB, [T][B][Z]
    __hip_bfloat16* WTe0 = (__hip_bfloat16*)alloc((size_t)G4_ * (U_ + D_) * 2);
    __hip_bfloat16* WTe1 = (__hip_bfloat16*)alloc((size_t)G4_ * (U_ + U_) * 2);
    __hip_bfloat16* WTd0 = (__hip_bfloat16*)alloc((size_t)G4_ * (U_ + Z_) * 2);
    __hip_bfloat16* WTd1 = (__hip_bfloat16*)alloc((size_t)G4_ * (U_ + U_) * 2);
    __hip_bfloat16* WmT  = (__hip_bfloat16*)alloc((size_t)Z_ * U_ * 2);
    __hip_bfloat16* WvT  = (__hip_bfloat16*)alloc((size_t)Z_ * U_ * 2);
    __hip_bfloat16* WoT  = (__hip_bfloat16*)alloc((size_t)D_ * U_ * 2);
    float* be0 = (float*)alloc(G4_ * 4);
    float* be1 = (float*)alloc(G4_ * 4);
    float* bd0 = (float*)alloc(G4_ * 4);
    float* bd1 = (float*)alloc(G4_ * 4);
    // per-layer ctrl: [8 roster][pad->64][MALL flags 4096] u32
    const int CTRLW = 64 + 4096;
    unsigned* ctrl = (unsigned*)alloc((size_t)4 * CTRLW * sizeof(unsigned));

    hipMemsetAsync(ctrl, 0, (size_t)4 * CTRLW * sizeof(unsigned), stream);

    // ---- prep: bf16 conversions + weight transpose/permutes ----
    convert_transpose<<<(B_ * T_ * D_ + 255) / 256, 256, 0, stream>>>(x, xb);

    auto cw = [&](const float* src, __hip_bfloat16* dst, int K, int Nrows, int Nsrc, int ldd, int koff, int perm) {
        conv_weight<<<(K * Nrows + 255) / 256, 256, 0, stream>>>(src, dst, K, Nrows, Nsrc, ldd, koff, perm);
    };
    cw(e0Wh, WTe0, U_, G4_, G4_, U_ + D_, 0, 1);
    cw(e0Wx, WTe0, D_, G4_, G4_, U_ + D_, U_, 1);
    cw(e1Wh, WTe1, U_, G4_, G4_, U_ + U_, 0, 1);
    cw(e1Wx, WTe1, U_, G4_, G4_, U_ + U_, U_, 1);
    cw(d0Wh, WTd0, U_, G4_, G4_, U_ + Z_, 0, 1);
    cw(d0Wx, WTd0, Z_, G4_, G4_, U_ + Z_, U_, 1);
    cw(d1Wh, WTd1, U_, G4_, G4_, U_ + U_, 0, 1);
    cw(d1Wx, WTd1, U_, G4_, G4_, U_ + U_, U_, 1);
    cw(Wm, WmT, U_, Z_, Z_, U_, 0, 0);
    cw(Wv, WvT, U_, Z_, Z_, U_, 0, 0);
    cw(Wo, WoT, U_, D_, D_, U_, 0, 0);
    conv_bias<<<G4_ / 256, 256, 0, stream>>>(e0b, be0);
    conv_bias<<<G4_ / 256, 256, 0, stream>>>(e1b, be1);
    conv_bias<<<G4_ / 256, 256, 0, stream>>>(d0b, bd0);
    conv_bias<<<G4_ / 256, 256, 0, stream>>>(d1b, bd1);

    // ---- encoder (persistent layers, 512 threads) ----
    lstm_layer_persist<D_><<<256, 512, 0, stream>>>(hsA, xb, WTe0, be0, ctrl + 0 * CTRLW);
    lstm_layer_persist<U_><<<256, 512, 0, stream>>>(hsB, hsA, WTe1, be1, ctrl + 1 * CTRLW);

    // ---- latent heads + reparameterize ----
    const size_t oRecon = 0;
    const size_t oE   = (size_t)B_ * T_ * D_;
    const size_t oZm  = oE + (size_t)B_ * T_ * Z_;
    const size_t oZlv = oZm + (size_t)B_ * T_ * Z_;
    const size_t oZ   = oZlv + (size_t)B_ * T_ * Z_;

    gemm_bias<<<dim3(B_ * T_ / 128, Z_ / 64), 256, 0, stream>>>(hsB, WmT, bm, out + oZm, U_, Z_);
    gemm_bias<<<dim3(B_ * T_ / 128, Z_ / 64), 256, 0, stream>>>(hsB, WvT, bv, out + oZlv, U_, Z_);
    reparam<<<(B_ * T_ * Z_ + 255) / 256, 256, 0, stream>>>(out + oZm, out + oZlv, eps,
                                                            out + oZ, out + oE, zb, B_ * T_ * Z_);

    // ---- decoder (persistent layers, 512 threads) ----
    lstm_layer_persist<Z_><<<256, 512, 0, stream>>>(hsA, zb, WTd0, bd0, ctrl + 2 * CTRLW);
    lstm_layer_persist<U_><<<256, 512, 0, stream>>>(hsB, hsA, WTd1, bd1, ctrl + 3 * CTRLW);

    // ---- output dense ----
    gemm_bias<<<dim3(B_ * T_ / 128, D_ / 64), 256, 0, stream>>>(hsB, WoT, bo, out + oRecon, U_, D_);
}